// Round 7
// baseline (3672.823 us; speedup 1.0000x reference)
//
#include <hip/hip_runtime.h>

// HydrAMP GRU, 25-step scan, B=131072, UNITS=66.
// One thread = one batch row, entire recurrence in registers.
// Weights staged to LDS as f16, transposed, K padded 66->72.
// t>=1 uses fused (kernel + recurrent) z/r matrix since x == h.
// output_len input (d_in[5]) is the constant 25 -> compile-time T_STEPS.
// (Resubmission: rounds 1-6 hit GPUAcquisitionTimeout, no measurement yet.)

#define UNITS   66
#define NW      198           // 3*UNITS
#define KPAD    72            // UNITS padded to multiple of 8 (ds_read_b128)
#define NPAIR   36            // KPAD/2
#define NCHUNK  9             // KPAD/8
#define T_STEPS 25
#define THREADS 512

typedef _Float16 h2v __attribute__((ext_vector_type(2)));
typedef _Float16 h8v __attribute__((ext_vector_type(8)));

#define SV(w, i) __builtin_shufflevector((w), (w), 2*(i), 2*(i)+1)

__device__ __forceinline__ h2v pack2(float a, float b) {
    h2v r; r[0] = (_Float16)a; r[1] = (_Float16)b; return r;
}

// 4 packed-f16 partial sums -> f32 (+bias)
__device__ __forceinline__ float red4(h2v a0, h2v a1, h2v a2, h2v a3, float bias) {
    h2v s01 = a0 + a1;
    h2v s23 = a2 + a3;
    return bias + (((float)s01[0] + (float)s01[1]) + ((float)s23[0] + (float)s23[1]));
}

__device__ __forceinline__ float sigmoid_f(float x) {
    return __builtin_amdgcn_rcpf(1.0f + __expf(-x));
}
__device__ __forceinline__ float tanh_f(float x) {
    return 1.0f - 2.0f * __builtin_amdgcn_rcpf(__expf(2.0f * x) + 1.0f);
}

__global__ __launch_bounds__(THREADS, 2)
void gru_persist(const float* __restrict__ inp, const float* __restrict__ st,
                 const float* __restrict__ wk, const float* __restrict__ wr,
                 const float* __restrict__ bs, float* __restrict__ out, int batch)
{
    // Transposed f16 weights: [output j][k], k padded to KPAD with zeros.
    __shared__ __align__(16) _Float16 KT[NW][KPAD];          // kernel^T (all 198 cols)
    __shared__ __align__(16) _Float16 WzrT[2*UNITS][KPAD];   // (kernel+recurrent)^T, z/r cols
    __shared__ __align__(16) _Float16 RhT[UNITS][KPAD];      // recurrent^T, h cols
    __shared__ float bias_s[NW];

    const int tid = threadIdx.x;

    // ---- stage weights (coalesced global reads, one-time) ----
    for (int idx = tid; idx < UNITS * NW; idx += THREADS) {
        int k = idx / NW, j = idx % NW;
        float kv = wk[idx], rv = wr[idx];
        KT[j][k] = (_Float16)kv;
        if (j < 2*UNITS) WzrT[j][k] = (_Float16)(kv + rv);
        else             RhT[j - 2*UNITS][k] = (_Float16)rv;
    }
    for (int idx = tid; idx < NW * (KPAD - UNITS); idx += THREADS) {
        int j = idx / (KPAD - UNITS);
        int k = UNITS + idx % (KPAD - UNITS);
        KT[j][k] = (_Float16)0.f;
        if (j < 2*UNITS) WzrT[j][k] = (_Float16)0.f;
        if (j < UNITS)   RhT[j][k]  = (_Float16)0.f;
    }
    for (int idx = tid; idx < NW; idx += THREADS) bias_s[idx] = bs[idx];
    __syncthreads();

    const int row = blockIdx.x * THREADS + tid;
    if (row >= batch) return;

    float h[UNITS];        // current hidden state, f32
    float z[UNITS];        // z gate, then reused for h_new
    h2v  h2[NPAIR];        // h packed f16 pairs (padded with zeros)
    h2v  rh2[NPAIR];       // (r*h) packed f16 pairs

    float* op = out + (size_t)row * (T_STEPS * UNITS);

    // ---------------- step 0 (general: x = input, h = state) ----------------
    // pre_zr = b + x@K_zr + h@R_zr = b + d@K_zr + h@(K_zr+R_zr), d = x - h
    // pre_h  = b_h + x@K_h + (r*h)@R_h
    {
        h2v d2[NPAIR];
        const float2* xp = reinterpret_cast<const float2*>(inp + (size_t)row * UNITS);
        const float2* sp = reinterpret_cast<const float2*>(st  + (size_t)row * UNITS);
        #pragma unroll
        for (int p = 0; p < UNITS/2; ++p) {
            float2 xv = xp[p], sv = sp[p];
            h[2*p] = sv.x; h[2*p+1] = sv.y;
            h2[p] = pack2(sv.x, sv.y);
            d2[p] = pack2(xv.x - sv.x, xv.y - sv.y);
        }
        #pragma unroll
        for (int p = UNITS/2; p < NPAIR; ++p) {
            h2[p] = pack2(0.f, 0.f); d2[p] = pack2(0.f, 0.f); rh2[p] = pack2(0.f, 0.f);
        }

        float rh_prev = 0.f;
        #pragma unroll
        for (int j = 0; j < 2*UNITS; ++j) {
            h2v a0 = pack2(0.f,0.f), a1 = a0, a2 = a0, a3 = a0;
            h2v b0 = a0, b1 = a0, b2 = a0, b3 = a0;
            #pragma unroll
            for (int c = 0; c < NCHUNK; ++c) {
                h8v wK = *reinterpret_cast<const h8v*>(&KT[j][c*8]);
                h8v wZ = *reinterpret_cast<const h8v*>(&WzrT[j][c*8]);
                a0 += d2[c*4+0] * SV(wK,0);
                a1 += d2[c*4+1] * SV(wK,1);
                a2 += d2[c*4+2] * SV(wK,2);
                a3 += d2[c*4+3] * SV(wK,3);
                b0 += h2[c*4+0] * SV(wZ,0);
                b1 += h2[c*4+1] * SV(wZ,1);
                b2 += h2[c*4+2] * SV(wZ,2);
                b3 += h2[c*4+3] * SV(wZ,3);
            }
            float pre = red4(a0,a1,a2,a3, bias_s[j]) + red4(b0,b1,b2,b3, 0.f);
            float g = sigmoid_f(pre);
            if (j < UNITS) z[j] = g;
            else {
                int jr = j - UNITS;
                float rhv = g * h[jr];
                if (jr & 1) rh2[jr >> 1] = pack2(rh_prev, rhv);
                else        rh_prev = rhv;
            }
        }
        // x2 = d2 + h2 (packed); d2 dead after this
        h2v x2[NPAIR];
        #pragma unroll
        for (int p = 0; p < NPAIR; ++p) x2[p] = d2[p] + h2[p];

        #pragma unroll
        for (int j = 0; j < UNITS; ++j) {
            h2v a0 = pack2(0.f,0.f), a1 = a0, a2 = a0, a3 = a0;
            h2v b0 = a0, b1 = a0, b2 = a0, b3 = a0;
            #pragma unroll
            for (int c = 0; c < NCHUNK; ++c) {
                h8v wK = *reinterpret_cast<const h8v*>(&KT[2*UNITS + j][c*8]);
                h8v wR = *reinterpret_cast<const h8v*>(&RhT[j][c*8]);
                a0 += x2[c*4+0] * SV(wK,0);
                a1 += x2[c*4+1] * SV(wK,1);
                a2 += x2[c*4+2] * SV(wK,2);
                a3 += x2[c*4+3] * SV(wK,3);
                b0 += rh2[c*4+0] * SV(wR,0);
                b1 += rh2[c*4+1] * SV(wR,1);
                b2 += rh2[c*4+2] * SV(wR,2);
                b3 += rh2[c*4+3] * SV(wR,3);
            }
            float pre = red4(a0,a1,a2,a3, bias_s[2*UNITS + j]) + red4(b0,b1,b2,b3, 0.f);
            float hh = tanh_f(pre);
            z[j] = z[j] * h[j] + (1.0f - z[j]) * hh;   // h_new into z[]
        }
        #pragma unroll
        for (int p = 0; p < UNITS/2; ++p) {
            float a = z[2*p], b = z[2*p+1];
            reinterpret_cast<float2*>(op)[p] = make_float2(a, b);
            h[2*p] = a; h[2*p+1] = b;
            h2[p] = pack2(a, b);
        }
    }

    // ---------------- steps 1..24 (fused: x == h) ----------------
    #pragma unroll 1
    for (int t = 1; t < T_STEPS; ++t) {
        float rh_prev = 0.f;
        // phase A: z and r gates via combined (K+R) z/r matrix
        #pragma unroll
        for (int j = 0; j < 2*UNITS; ++j) {
            h2v a0 = pack2(0.f,0.f), a1 = a0, a2 = a0, a3 = a0;
            #pragma unroll
            for (int c = 0; c < NCHUNK; ++c) {
                h8v w = *reinterpret_cast<const h8v*>(&WzrT[j][c*8]);
                a0 += h2[c*4+0] * SV(w,0);
                a1 += h2[c*4+1] * SV(w,1);
                a2 += h2[c*4+2] * SV(w,2);
                a3 += h2[c*4+3] * SV(w,3);
            }
            float g = sigmoid_f(red4(a0,a1,a2,a3, bias_s[j]));
            if (j < UNITS) z[j] = g;
            else {
                int jr = j - UNITS;
                float rhv = g * h[jr];
                if (jr & 1) rh2[jr >> 1] = pack2(rh_prev, rhv);
                else        rh_prev = rhv;
            }
        }
        // phase B: candidate hh and blend
        #pragma unroll
        for (int j = 0; j < UNITS; ++j) {
            h2v a0 = pack2(0.f,0.f), a1 = a0, a2 = a0, a3 = a0;
            h2v b0 = a0, b1 = a0, b2 = a0, b3 = a0;
            #pragma unroll
            for (int c = 0; c < NCHUNK; ++c) {
                h8v wK = *reinterpret_cast<const h8v*>(&KT[2*UNITS + j][c*8]);
                h8v wR = *reinterpret_cast<const h8v*>(&RhT[j][c*8]);
                a0 += h2[c*4+0] * SV(wK,0);
                a1 += h2[c*4+1] * SV(wK,1);
                a2 += h2[c*4+2] * SV(wK,2);
                a3 += h2[c*4+3] * SV(wK,3);
                b0 += rh2[c*4+0] * SV(wR,0);
                b1 += rh2[c*4+1] * SV(wR,1);
                b2 += rh2[c*4+2] * SV(wR,2);
                b3 += rh2[c*4+3] * SV(wR,3);
            }
            float pre = red4(a0,a1,a2,a3, bias_s[2*UNITS + j]) + red4(b0,b1,b2,b3, 0.f);
            float hh = tanh_f(pre);
            z[j] = z[j] * h[j] + (1.0f - z[j]) * hh;   // h_new into z[]
        }
        // epilogue: write output, update h / packed h
        float* opt = op + t * UNITS;
        #pragma unroll
        for (int p = 0; p < UNITS/2; ++p) {
            float a = z[2*p], b = z[2*p+1];
            reinterpret_cast<float2*>(opt)[p] = make_float2(a, b);
            h[2*p] = a; h[2*p+1] = b;
            h2[p] = pack2(a, b);
        }
    }
}

extern "C" void kernel_launch(void* const* d_in, const int* in_sizes, int n_in,
                              void* d_out, int out_size, void* d_ws, size_t ws_size,
                              hipStream_t stream) {
    const float* inp = (const float*)d_in[0];   // input_  [B,66]
    const float* st  = (const float*)d_in[1];   // state   [B,66]
    const float* wk  = (const float*)d_in[2];   // kernel  [66,198]
    const float* wr  = (const float*)d_in[3];   // recurrent_kernel [66,198]
    const float* bs  = (const float*)d_in[4];   // bias [198]
    // d_in[5] = output_len (always 25, compile-time T_STEPS)
    float* out = (float*)d_out;                 // [B,25,66] f32

    int batch = in_sizes[0] / UNITS;            // 131072
    int grid = (batch + THREADS - 1) / THREADS; // 256 blocks -> 1 per CU
    gru_persist<<<grid, THREADS, 0, stream>>>(inp, st, wk, wr, bs, out, batch);
}